// Round 7
// baseline (427.026 us; speedup 1.0000x reference)
//
#include <hip/hip_runtime.h>

#define D 64
#define BIN_SHIFT 7
#define BIN_SIZE 128
#define MAX_BINS 1024
#define BINCAP 2048              // bin load ~ Poisson(1598); P(>2033) < 1e-25
#define K1_THREADS 1024
#define K1_EPT 8
#define K1_EPB (K1_THREADS * K1_EPT)
#define K2_THREADS 512

// rec packing: tail[16:0] | rel[21:17] | head_local[28:22]

// ---------- K1: block-local counting-sort of edges into padded bin regions ----
__global__ void __launch_bounds__(K1_THREADS)
bin_sort_kernel(const int* __restrict__ head,
                const int* __restrict__ tail,
                const int* __restrict__ etype,
                int* __restrict__ binCount,     // [nbins] global cursors
                unsigned* __restrict__ recs,    // [nbins * BINCAP]
                int nbins, int n_edges) {
    __shared__ int hist[MAX_BINS];
    __shared__ int pos[MAX_BINS];
    int tid = threadIdx.x;
    for (int b = tid; b < nbins; b += K1_THREADS) hist[b] = 0;
    __syncthreads();

    long blockBase = (long)blockIdx.x * K1_EPB;
    int hv[K1_EPT];
#pragma unroll
    for (int k = 0; k < K1_EPT; k++) {            // coalesced head reads
        long e = blockBase + (long)k * K1_THREADS + tid;
        hv[k] = (e < n_edges) ? head[e] : -1;
        if (hv[k] >= 0) atomicAdd(&hist[hv[k] >> BIN_SHIFT], 1);
    }
    __syncthreads();

    // reserve one contiguous run per (block, bin)
    for (int b = tid; b < nbins; b += K1_THREADS) {
        int c = hist[b];
        pos[b] = (c > 0) ? atomicAdd(&binCount[b], c) : 0;
    }
    __syncthreads();

#pragma unroll
    for (int k = 0; k < K1_EPT; k++) {
        int h = hv[k];
        if (h >= 0) {
            long e = blockBase + (long)k * K1_THREADS + tid;
            int b = h >> BIN_SHIFT;
            int r = atomicAdd(&pos[b], 1);        // global slot within bin region
            if (r < BINCAP)
                recs[(long)b * BINCAP + r] =
                    (unsigned)tail[e] | ((unsigned)etype[e] << 17)
                  | ((unsigned)(h & (BIN_SIZE - 1)) << 22);
        }
    }
}

// ---------- K2: per-bin LDS counting-sort by head + f4 gather-aggregate -------
__global__ void __launch_bounds__(K2_THREADS)
aggregate_bin_kernel(const float* __restrict__ emb,
                     const float* __restrict__ weight,
                     const unsigned* __restrict__ recs,
                     const int* __restrict__ binCount,
                     float* __restrict__ out, int n_ent) {
    __shared__ unsigned raw[BINCAP];
    __shared__ unsigned sorted[BINCAP + 16];   // +16: gather loop over-reads <=15
    __shared__ int hist[BIN_SIZE];
    __shared__ int off[BIN_SIZE];
    __shared__ int cur[BIN_SIZE];

    int tid = threadIdx.x;
    int b = blockIdx.x;
    int n = min(binCount[b], BINCAP);

    for (int i = tid; i < BINCAP + 16; i += K2_THREADS) sorted[i] = 0u;
    if (tid < BIN_SIZE) hist[tid] = 0;
    __syncthreads();

    const unsigned* gr = recs + (long)b * BINCAP;
    for (int i = tid; i < n; i += K2_THREADS) {   // contiguous ~6.4KB read
        unsigned q = gr[i];
        raw[i] = q;
        atomicAdd(&hist[(q >> 22) & 127], 1);
    }
    __syncthreads();

    // exclusive scan of hist[128] (Hillis-Steele, lanes 0..127; all threads sync)
    int v = 0;
    if (tid < BIN_SIZE) { v = hist[tid]; off[tid] = v; }
    __syncthreads();
    for (int s = 1; s < BIN_SIZE; s <<= 1) {
        int x = 0;
        if (tid < BIN_SIZE && tid >= s) x = off[tid - s];
        __syncthreads();
        if (tid < BIN_SIZE) off[tid] += x;
        __syncthreads();
    }
    if (tid < BIN_SIZE) { off[tid] -= v; cur[tid] = off[tid]; }
    __syncthreads();

    for (int i = tid; i < n; i += K2_THREADS) {   // LDS scatter into sorted order
        unsigned q = raw[i];
        int p = atomicAdd(&cur[(q >> 22) & 127], 1);
        sorted[p] = q;
    }
    __syncthreads();

    int lane = tid & 63;
    int wave = tid >> 6;          // 8 waves, 16 heads each
    int g = lane >> 4;            // edge subgroup
    int c = lane & 15;            // feature quad
    int hbase = b << BIN_SHIFT;

    for (int hl = wave; hl < BIN_SIZE; hl += 8) {
        if (hbase + hl >= n_ent) break;
        int o = off[hl];
        int deg = hist[hl];
        float4 acc = make_float4(0.f, 0.f, 0.f, 0.f);
        for (int i = 0; i < deg; i += 16) {
            int e0 = i + g, e1 = i + 4 + g, e2 = i + 8 + g, e3 = i + 12 + g;
            unsigned q0 = sorted[o + e0];   // same addr across 16 lanes: LDS broadcast
            unsigned q1 = sorted[o + e1];
            unsigned q2 = sorted[o + e2];
            unsigned q3 = sorted[o + e3];
            // 8 independent float4 loads in flight (4 rows + 4 weight rows)
            float4 v0 = *(const float4*)&emb[(long)(q0 & 0x1FFFF) * D + c * 4];
            float4 v1 = *(const float4*)&emb[(long)(q1 & 0x1FFFF) * D + c * 4];
            float4 v2 = *(const float4*)&emb[(long)(q2 & 0x1FFFF) * D + c * 4];
            float4 v3 = *(const float4*)&emb[(long)(q3 & 0x1FFFF) * D + c * 4];
            float4 w0 = *(const float4*)&weight[(((q0 >> 17) & 31) << 6) + c * 4];
            float4 w1 = *(const float4*)&weight[(((q1 >> 17) & 31) << 6) + c * 4];
            float4 w2 = *(const float4*)&weight[(((q2 >> 17) & 31) << 6) + c * 4];
            float4 w3 = *(const float4*)&weight[(((q3 >> 17) & 31) << 6) + c * 4];
            float m0 = (e0 < deg) ? 1.f : 0.f;
            float m1 = (e1 < deg) ? 1.f : 0.f;
            float m2 = (e2 < deg) ? 1.f : 0.f;
            float m3 = (e3 < deg) ? 1.f : 0.f;
            acc.x += m0 * v0.x * w0.x; acc.y += m0 * v0.y * w0.y;
            acc.z += m0 * v0.z * w0.z; acc.w += m0 * v0.w * w0.w;
            acc.x += m1 * v1.x * w1.x; acc.y += m1 * v1.y * w1.y;
            acc.z += m1 * v1.z * w1.z; acc.w += m1 * v1.w * w1.w;
            acc.x += m2 * v2.x * w2.x; acc.y += m2 * v2.y * w2.y;
            acc.z += m2 * v2.z * w2.z; acc.w += m2 * v2.w * w2.w;
            acc.x += m3 * v3.x * w3.x; acc.y += m3 * v3.y * w3.y;
            acc.z += m3 * v3.z * w3.z; acc.w += m3 * v3.w * w3.w;
        }
        // combine the 4 edge-subgroups
        acc.x += __shfl_xor(acc.x, 16); acc.y += __shfl_xor(acc.y, 16);
        acc.z += __shfl_xor(acc.z, 16); acc.w += __shfl_xor(acc.w, 16);
        acc.x += __shfl_xor(acc.x, 32); acc.y += __shfl_xor(acc.y, 32);
        acc.z += __shfl_xor(acc.z, 32); acc.w += __shfl_xor(acc.w, 32);
        if (g == 0) {
            float inv = 1.f / fmaxf((float)deg, 1.f);
            *(float4*)&out[(long)(hbase + hl) * D + c * 4] =
                make_float4(acc.x * inv, acc.y * inv, acc.z * inv, acc.w * inv);
        }
    }
}

// ---------- Fallback (R1 atomic version) for out-of-envelope shapes ----------
__global__ void fb_scatter(const float* __restrict__ emb, const int* __restrict__ head,
                           const int* __restrict__ tail, const int* __restrict__ etype,
                           const float* __restrict__ weight, float* __restrict__ out,
                           float* __restrict__ cnt, int n_edges) {
    int gtid = blockIdx.x * blockDim.x + threadIdx.x;
    int e = gtid >> 6, lane = threadIdx.x & 63;
    if (e >= n_edges) return;
    int h = head[e], t = tail[e], r = etype[e];
    atomicAdd(&out[(long)h * D + lane], emb[(long)t * D + lane] * weight[r * D + lane]);
    if (lane == 0) atomicAdd(&cnt[h], 1.0f);
}
__global__ void fb_divide(float* __restrict__ out, const float* __restrict__ cnt, int n) {
    int i = blockIdx.x * blockDim.x + threadIdx.x;
    if (i < n) out[i] = out[i] / fmaxf(cnt[i >> 6], 1.0f);
}

// ===========================================================================

extern "C" void kernel_launch(void* const* d_in, const int* in_sizes, int n_in,
                              void* d_out, int out_size, void* d_ws, size_t ws_size,
                              hipStream_t stream) {
    const float* emb    = (const float*)d_in[0];  // [N_ENT, 64] fp32
    const int*   eidx   = (const int*)  d_in[1];  // [2, E] int32
    const int*   etype  = (const int*)  d_in[2];  // [E] int32
    const float* weight = (const float*)d_in[3];  // [32, 64] fp32
    float* out = (float*)d_out;

    int n_edges = in_sizes[2];
    int n_ent   = out_size / D;
    const int* head = eidx;
    const int* tail = eidx + n_edges;

    int nbins = (n_ent + BIN_SIZE - 1) >> BIN_SHIFT;
    size_t need = sizeof(int) * ((size_t)nbins * (BINCAP + 1));
    bool ok = (n_ent <= 131072) && (nbins <= MAX_BINS) && (ws_size >= need) &&
              ((long)n_edges * 128 / n_ent + 600 < BINCAP);  // mean bin load margin

    if (ok) {
        int* binCount  = (int*)d_ws;                     // [nbins]
        unsigned* recs = (unsigned*)(binCount + nbins);  // [nbins * BINCAP]

        hipMemsetAsync(binCount, 0, (size_t)nbins * sizeof(int), stream);

        int nblocks = (n_edges + K1_EPB - 1) / K1_EPB;   // 153 for 1.25M
        bin_sort_kernel<<<nblocks, K1_THREADS, 0, stream>>>(
            head, tail, etype, binCount, recs, nbins, n_edges);

        aggregate_bin_kernel<<<nbins, K2_THREADS, 0, stream>>>(
            emb, weight, recs, binCount, out, n_ent);
    } else {
        float* cnt = (float*)d_ws;
        hipMemsetAsync(out, 0, (size_t)out_size * sizeof(float), stream);
        hipMemsetAsync(cnt, 0, (size_t)n_ent * sizeof(float), stream);
        long tt = (long)n_edges * 64;
        fb_scatter<<<(int)((tt + 255) / 256), 256, 0, stream>>>(
            emb, head, tail, etype, weight, out, cnt, n_edges);
        fb_divide<<<(out_size + 255) / 256, 256, 0, stream>>>(out, cnt, out_size);
    }
}

// Round 8
// 157.619 us; speedup vs baseline: 2.7092x; 2.7092x over previous
//
#include <hip/hip_runtime.h>

#define D 64
#define BIN_SHIFT 7
#define BIN_SIZE 128
#define MAX_BINS 1024
#define BINCAP 2560              // bin load ~ Poisson(1600), sigma 40 -> +24 sigma
#define K1_THREADS 1024
#define K1_EPT 8
#define K1_EPB (K1_THREADS * K1_EPT)
#define K2_THREADS 512

// rec packing: tail[16:0] | rel[21:17] | head_local[28:22]

// ---------- K1: block-local counting-sort of edges into padded bin regions ----
__global__ void __launch_bounds__(K1_THREADS)
bin_sort_kernel(const int* __restrict__ head,
                const int* __restrict__ tail,
                const int* __restrict__ etype,
                int* __restrict__ binCount,     // [nbins] global cursors
                unsigned* __restrict__ recs,    // [nbins * BINCAP]
                int nbins, int n_edges) {
    __shared__ int hist[MAX_BINS];
    __shared__ int pos[MAX_BINS];
    int tid = threadIdx.x;
    for (int b = tid; b < nbins; b += K1_THREADS) hist[b] = 0;
    __syncthreads();

    long blockBase = (long)blockIdx.x * K1_EPB;
    int hv[K1_EPT];
#pragma unroll
    for (int k = 0; k < K1_EPT; k++) {            // coalesced head reads
        long e = blockBase + (long)k * K1_THREADS + tid;
        hv[k] = (e < n_edges) ? head[e] : -1;
        if (hv[k] >= 0) atomicAdd(&hist[hv[k] >> BIN_SHIFT], 1);
    }
    __syncthreads();

    // reserve one contiguous run per (block, bin)
    for (int b = tid; b < nbins; b += K1_THREADS) {
        int c = hist[b];
        pos[b] = (c > 0) ? atomicAdd(&binCount[b], c) : 0;
    }
    __syncthreads();

#pragma unroll
    for (int k = 0; k < K1_EPT; k++) {
        int h = hv[k];
        if (h >= 0) {
            long e = blockBase + (long)k * K1_THREADS + tid;
            int b = h >> BIN_SHIFT;
            int r = atomicAdd(&pos[b], 1);        // global slot within bin region
            if (r < BINCAP)
                recs[(long)b * BINCAP + r] =
                    (unsigned)tail[e] | ((unsigned)etype[e] << 17)
                  | ((unsigned)(h & (BIN_SIZE - 1)) << 22);
        }
    }
}

// ---------- K2: per-bin LDS counting-sort by head + f4 gather-aggregate -------
__global__ void __launch_bounds__(K2_THREADS)
aggregate_bin_kernel(const float* __restrict__ emb,
                     const float* __restrict__ weight,
                     const unsigned* __restrict__ recs,
                     const int* __restrict__ binCount,
                     float* __restrict__ out, int n_ent) {
    __shared__ unsigned raw[BINCAP];
    __shared__ unsigned sorted[BINCAP + 16];   // +16: gather loop over-reads <=15
    __shared__ int hist[BIN_SIZE];
    __shared__ int off[BIN_SIZE];
    __shared__ int cur[BIN_SIZE];

    int tid = threadIdx.x;
    int b = blockIdx.x;
    int n = min(binCount[b], BINCAP);

    for (int i = tid; i < BINCAP + 16; i += K2_THREADS) sorted[i] = 0u;
    if (tid < BIN_SIZE) hist[tid] = 0;
    __syncthreads();

    const unsigned* gr = recs + (long)b * BINCAP;
    for (int i = tid; i < n; i += K2_THREADS) {   // contiguous ~8KB read
        unsigned q = gr[i];
        raw[i] = q;
        atomicAdd(&hist[(q >> 22) & 127], 1);
    }
    __syncthreads();

    // exclusive scan of hist[128] (Hillis-Steele; all threads hit barriers)
    int v = 0;
    if (tid < BIN_SIZE) { v = hist[tid]; off[tid] = v; }
    __syncthreads();
    for (int s = 1; s < BIN_SIZE; s <<= 1) {
        int x = 0;
        if (tid < BIN_SIZE && tid >= s) x = off[tid - s];
        __syncthreads();
        if (tid < BIN_SIZE) off[tid] += x;
        __syncthreads();
    }
    if (tid < BIN_SIZE) { off[tid] -= v; cur[tid] = off[tid]; }
    __syncthreads();

    for (int i = tid; i < n; i += K2_THREADS) {   // LDS scatter into sorted order
        unsigned q = raw[i];
        int p = atomicAdd(&cur[(q >> 22) & 127], 1);
        sorted[p] = q;
    }
    __syncthreads();

    int lane = tid & 63;
    int wave = tid >> 6;          // 8 waves, 16 heads each
    int g = lane >> 4;            // edge subgroup
    int c = lane & 15;            // feature quad
    int hbase = b << BIN_SHIFT;

    for (int hl = wave; hl < BIN_SIZE; hl += 8) {
        if (hbase + hl >= n_ent) break;
        int o = off[hl];
        int deg = hist[hl];
        float4 acc = make_float4(0.f, 0.f, 0.f, 0.f);
        for (int i = 0; i < deg; i += 16) {
            int e0 = i + g, e1 = i + 4 + g, e2 = i + 8 + g, e3 = i + 12 + g;
            unsigned q0 = sorted[o + e0];   // same addr across 16 lanes: LDS broadcast
            unsigned q1 = sorted[o + e1];
            unsigned q2 = sorted[o + e2];
            unsigned q3 = sorted[o + e3];
            // 8 independent float4 loads in flight (4 emb rows + 4 weight rows)
            float4 v0 = *(const float4*)&emb[(long)(q0 & 0x1FFFF) * D + c * 4];
            float4 v1 = *(const float4*)&emb[(long)(q1 & 0x1FFFF) * D + c * 4];
            float4 v2 = *(const float4*)&emb[(long)(q2 & 0x1FFFF) * D + c * 4];
            float4 v3 = *(const float4*)&emb[(long)(q3 & 0x1FFFF) * D + c * 4];
            float4 w0 = *(const float4*)&weight[(((q0 >> 17) & 31) << 6) + c * 4];
            float4 w1 = *(const float4*)&weight[(((q1 >> 17) & 31) << 6) + c * 4];
            float4 w2 = *(const float4*)&weight[(((q2 >> 17) & 31) << 6) + c * 4];
            float4 w3 = *(const float4*)&weight[(((q3 >> 17) & 31) << 6) + c * 4];
            float m0 = (e0 < deg) ? 1.f : 0.f;
            float m1 = (e1 < deg) ? 1.f : 0.f;
            float m2 = (e2 < deg) ? 1.f : 0.f;
            float m3 = (e3 < deg) ? 1.f : 0.f;
            acc.x += m0 * v0.x * w0.x; acc.y += m0 * v0.y * w0.y;
            acc.z += m0 * v0.z * w0.z; acc.w += m0 * v0.w * w0.w;
            acc.x += m1 * v1.x * w1.x; acc.y += m1 * v1.y * w1.y;
            acc.z += m1 * v1.z * w1.z; acc.w += m1 * v1.w * w1.w;
            acc.x += m2 * v2.x * w2.x; acc.y += m2 * v2.y * w2.y;
            acc.z += m2 * v2.z * w2.z; acc.w += m2 * v2.w * w2.w;
            acc.x += m3 * v3.x * w3.x; acc.y += m3 * v3.y * w3.y;
            acc.z += m3 * v3.z * w3.z; acc.w += m3 * v3.w * w3.w;
        }
        // combine the 4 edge-subgroups
        acc.x += __shfl_xor(acc.x, 16); acc.y += __shfl_xor(acc.y, 16);
        acc.z += __shfl_xor(acc.z, 16); acc.w += __shfl_xor(acc.w, 16);
        acc.x += __shfl_xor(acc.x, 32); acc.y += __shfl_xor(acc.y, 32);
        acc.z += __shfl_xor(acc.z, 32); acc.w += __shfl_xor(acc.w, 32);
        if (g == 0) {
            float inv = 1.f / fmaxf((float)deg, 1.f);
            *(float4*)&out[(long)(hbase + hl) * D + c * 4] =
                make_float4(acc.x * inv, acc.y * inv, acc.z * inv, acc.w * inv);
        }
    }
}

// ---------- Fallback (R1 atomic version) for out-of-envelope shapes ----------
__global__ void fb_scatter(const float* __restrict__ emb, const int* __restrict__ head,
                           const int* __restrict__ tail, const int* __restrict__ etype,
                           const float* __restrict__ weight, float* __restrict__ out,
                           float* __restrict__ cnt, int n_edges) {
    int gtid = blockIdx.x * blockDim.x + threadIdx.x;
    int e = gtid >> 6, lane = threadIdx.x & 63;
    if (e >= n_edges) return;
    int h = head[e], t = tail[e], r = etype[e];
    atomicAdd(&out[(long)h * D + lane], emb[(long)t * D + lane] * weight[r * D + lane]);
    if (lane == 0) atomicAdd(&cnt[h], 1.0f);
}
__global__ void fb_divide(float* __restrict__ out, const float* __restrict__ cnt, int n) {
    int i = blockIdx.x * blockDim.x + threadIdx.x;
    if (i < n) out[i] = out[i] / fmaxf(cnt[i >> 6], 1.0f);
}

// ===========================================================================

extern "C" void kernel_launch(void* const* d_in, const int* in_sizes, int n_in,
                              void* d_out, int out_size, void* d_ws, size_t ws_size,
                              hipStream_t stream) {
    const float* emb    = (const float*)d_in[0];  // [N_ENT, 64] fp32
    const int*   eidx   = (const int*)  d_in[1];  // [2, E] int32
    const int*   etype  = (const int*)  d_in[2];  // [E] int32
    const float* weight = (const float*)d_in[3];  // [32, 64] fp32
    float* out = (float*)d_out;

    int n_edges = in_sizes[2];
    int n_ent   = out_size / D;
    const int* head = eidx;
    const int* tail = eidx + n_edges;

    int nbins = (n_ent + BIN_SIZE - 1) >> BIN_SHIFT;       // 782 for 100k
    size_t need = sizeof(int) * ((size_t)nbins * (BINCAP + 1));  // ~8MB
    long mean_load = (n_ent > 0) ? ((long)n_edges * BIN_SIZE / n_ent) : 0;  // 1600
    bool ok = (n_ent <= 131072) && (nbins <= MAX_BINS) && (ws_size >= need) &&
              (mean_load + 700 <= BINCAP);   // 1600+700=2300 <= 2560: binned path runs

    if (ok) {
        int* binCount  = (int*)d_ws;                     // [nbins]
        unsigned* recs = (unsigned*)(binCount + nbins);  // [nbins * BINCAP]

        hipMemsetAsync(binCount, 0, (size_t)nbins * sizeof(int), stream);

        int nblocks = (n_edges + K1_EPB - 1) / K1_EPB;   // 153 for 1.25M
        bin_sort_kernel<<<nblocks, K1_THREADS, 0, stream>>>(
            head, tail, etype, binCount, recs, nbins, n_edges);

        aggregate_bin_kernel<<<nbins, K2_THREADS, 0, stream>>>(
            emb, weight, recs, binCount, out, n_ent);
    } else {
        float* cnt = (float*)d_ws;
        hipMemsetAsync(out, 0, (size_t)out_size * sizeof(float), stream);
        hipMemsetAsync(cnt, 0, (size_t)n_ent * sizeof(float), stream);
        long tt = (long)n_edges * 64;
        fb_scatter<<<(int)((tt + 255) / 256), 256, 0, stream>>>(
            emb, head, tail, etype, weight, out, cnt, n_edges);
        fb_divide<<<(out_size + 255) / 256, 256, 0, stream>>>(out, cnt, out_size);
    }
}